// Round 6
// baseline (178.708 us; speedup 1.0000x reference)
//
#include <hip/hip_runtime.h>

// Radon transform, MI355X. B=4, IMG=256, NA=512.
// R6 = R5 with the DS pipe halved: 2x2 tap quad per 8B LDS word -> ONE
// ds_read_b64 per bilinear sample (R5: ds_read2_b32 = 2 accesses + 9.9M
// conflict cycles). XOR swizzle e^=(e>>5)&7 kills the angle-dependent bank
// pileup. 74 KB LDS -> 2 blocks/CU (16 waves). Everything else as R5:
// slab-parallel blocks, adaptive row/col orientation via transposed copy,
// ws[q][b][a][w] partials + transpose-reduce, med3 pc clamp, fdot2 epilogue.

typedef _Float16 f16;
typedef _Float16 f16x2 __attribute__((ext_vector_type(2)));
typedef _Float16 f16x4 __attribute__((ext_vector_type(4)));
typedef __fp16   h16x2 __attribute__((ext_vector_type(2)));

#define SRQ   36            // quad rows per column (Ri in [0,35])
#define NC    257           // pair-columns X = 0..256
#define LDSQ  (NC * SRQ)    // 9252 8B words
#define LDSP  9256          // padded for swizzle (max e' = 9255)

// one bilinear sample: quad word (X,rr) = {P[r][X-1],P[r][X],P[r+1][X-1],P[r+1][X]}
#define SAMP(PC, PR, ACC) do {                                  \
    float pc_ = __builtin_amdgcn_fmed3f((PC), 0.0f, 256.999f);  \
    float pr_ = (PR);                                           \
    int   Xi_ = (int)pc_;                                       \
    int   Ri_ = (int)pr_;                                       \
    float wc_ = __builtin_amdgcn_fractf(pc_);                   \
    float wr_ = __builtin_amdgcn_fractf(pr_);                   \
    int   e_  = Xi_ * SRQ + Ri_;                                \
    e_ ^= (e_ >> 5) & 7;                                        \
    f16x4 qd_ = lds4[e_];                                       \
    f16x2 lo_ = __builtin_shufflevector(qd_, qd_, 0, 1);        \
    f16x2 hi_ = __builtin_shufflevector(qd_, qd_, 2, 3);        \
    f16   wrh_ = (f16)wr_;                                      \
    f16x2 wv_  = {wrh_, wrh_};                                  \
    f16x2 t_   = lo_ + wv_ * (hi_ - lo_);                       \
    h16x2 wp_  = __builtin_amdgcn_cvt_pkrtz(1.0f - wc_, wc_);   \
    (ACC) = __builtin_amdgcn_fdot2(__builtin_bit_cast(h16x2, t_), wp_, (ACC), false); \
} while (0)

__global__ __launch_bounds__(256) void transpose_k(const float* __restrict__ img,
                                                   float* __restrict__ imT) {
    __shared__ float tl[32][33];
    const int bx = blockIdx.x;                    // 256 = b(4) x ty(8) x tx(8)
    const int x0 = (bx & 7) << 5, y0 = ((bx >> 3) & 7) << 5, b = bx >> 6;
    const int lane = threadIdx.x & 31, rw = threadIdx.x >> 5;
    const float* ib = img + (b << 16);
    float*       tb = imT + (b << 16);
#pragma unroll
    for (int p = 0; p < 4; ++p) {
        int row = rw + (p << 3);
        tl[row][lane] = ib[((y0 + row) << 8) + x0 + lane];
    }
    __syncthreads();
#pragma unroll
    for (int p = 0; p < 4; ++p) {
        int row = rw + (p << 3);
        tb[((x0 + row) << 8) + y0 + lane] = tl[lane][row];
    }
}

__global__ __launch_bounds__(512, 4) void radon_k(const float* __restrict__ img,
                                                  const float* __restrict__ imT,
                                                  float* __restrict__ ws2) {
    __shared__ f16x4 lds4[LDSP];
    const int tid = threadIdx.x;
    const int bx  = blockIdx.x;                   // 2048 = b(4) x g(64) x q(8)
    const int q = bx & 7, g = (bx >> 3) & 63, b = bx >> 9;
    const int rbase = (q << 5) - 2;
    const bool colC = (g >= 16) && (g < 48);      // a in [128,384): column slabs
    const float* src = (colC ? imT : img) + (b << 16);

    // ---- stage quads: X fastest across threads -> coalesced 4-stream reads
    for (int u = tid; u < LDSQ; u += 512) {
        int rr = u / NC;
        int X  = u - rr * NC;
        int r0 = rbase + rr;
        float a0 = 0.f, b0 = 0.f, a1 = 0.f, b1 = 0.f;
        const float* rp0 = src + (r0 << 8);
        const bool c0 = X > 0, c1 = X < 256;
        if ((unsigned)r0 < 256u) {
            if (c0) a0 = rp0[X - 1];
            if (c1) b0 = rp0[X];
        }
        if ((unsigned)(r0 + 1) < 256u) {
            if (c0) a1 = rp0[256 + X - 1];
            if (c1) b1 = rp0[256 + X];
        }
        f16x4 w4; w4.x = (f16)a0; w4.y = (f16)b0; w4.z = (f16)a1; w4.w = (f16)b1;
        int e = X * SRQ + rr;
        e ^= (e >> 5) & 7;
        lds4[e] = w4;
    }
    __syncthreads();

    const int   w   = tid & 255, sub = tid >> 8;  // angle uniform per wave
    const float xw  = (float)w - 127.5f;
    const float B0  = (q == 0) ? -1.25f  : (float)(q << 5);
    const float B1  = (q == 7) ? 257.25f : (float)((q << 5) + 32);

    for (int k = 0; k < 4; ++k) {
        const int j = (k << 1) | sub;
        const int a = (g << 3) | j;
        const float th  = (float)a * 6.1359231515425649e-3f;    // a*pi/512
        const float sth = __sinf(th), cth = __cosf(th);         // same in all blocks
        const float Ax = fmaf(cth, xw, fmaf(sth, -127.5f, 127.5f));
        const float Ay = fmaf(-sth, xw, fmaf(cth, -127.5f, 127.5f));
        // role assignment: col coord (pair dim, small slope) / row coord (slab dim)
        float cs, As, rs, Ar;
        if (colC) { cs = cth; As = Ay; rs = sth; Ar = Ax; }
        else      { cs = sth; As = Ax; rs = cth; Ar = Ay; }

        // ---- slab ownership on r(h)=Ar+h*rs in [B0,B1); |rs|>=0.707, exact
        // ceil/floor partition (adjacent q share identical boundary floats)
        const float invr = 1.0f / rs;
        const float tA = (B0 - Ar) * invr, tB = (B1 - Ar) * invr;
        int h0, h1;
        if (rs > 0.f) { h0 = (int)ceilf(tA);      h1 = (int)ceilf(tB) - 1; }
        else          { h0 = (int)floorf(tB) + 1; h1 = (int)floorf(tA);   }

        // ---- col validity v(h)=As+h*cs in (-1,256); cs signed, may be ~0
        if (cs != 0.f) {
            const float invc = 1.0f / cs;
            float ta = (-1.0f - As) * invc, tb = (256.0f - As) * invc;
            ta = fmaxf(fminf(ta, 400.f), -400.f);
            tb = fmaxf(fminf(tb, 400.f), -400.f);
            if (cs > 0.f) { h0 = max(h0, (int)ceilf(ta));      h1 = min(h1, (int)ceilf(tb) - 1); }
            else          { h0 = max(h0, (int)floorf(tb) + 1); h1 = min(h1, (int)floorf(ta));   }
        } else if (As <= -1.f || As >= 256.f) {
            h1 = h0 - 1;                          // constant col coord, out of range
        }
        h0 = max(h0, 0); h1 = min(h1, 255);

        float acc0 = 0.f, acc1 = 0.f;
        if (h0 <= h1) {
            const float h0f = (float)h0;
            float pcA = fmaf(h0f, cs, As + 1.0f);          // col coord + 1
            float prA = fmaf(h0f, rs, Ar - (float)rbase);  // slab-local row, (0.7,35.3)
            float pcB = pcA + cs, prB = prA + rs;
            const float cs2 = cs + cs, rs2 = rs + rs;
            const int n = h1 - h0 + 1;
            int i = 0;
            for (; i + 2 <= n; i += 2) {          // dual chains: 2 ds_read_b64 in flight
                SAMP(pcA, prA, acc0);
                SAMP(pcB, prB, acc1);
                pcA += cs2; prA += rs2; pcB += cs2; prB += rs2;
            }
            if (n & 1) SAMP(pcA, prA, acc0);
        }
        // always store (ws poisoned 0xAA); wave-coalesced 256B segments
        ws2[((((q << 2) + b) << 9) | a) * 256 + w] = acc0 + acc1;
    }
}

__global__ __launch_bounds__(256) void reduce_k(const float* __restrict__ ws2,
                                                float* __restrict__ out) {
    __shared__ float s[32][33];
    const int bx = blockIdx.x;                    // 512 = b(4) x at(16) x wt(8)
    const int wt = bx & 7, at = (bx >> 3) & 15, b = bx >> 7;
    const int a0 = at << 5, w0 = wt << 5;
    const int wl = threadIdx.x & 31, r8 = threadIdx.x >> 5;
#pragma unroll
    for (int p = 0; p < 4; ++p) {
        int ar = r8 + (p << 3);
        int a  = a0 + ar;
        float acc = 0.f;
#pragma unroll
        for (int qq = 0; qq < 8; ++qq)
            acc += ws2[(((((qq << 2) + b) << 9) | a) << 8) | (w0 + wl)];
        s[ar][wl] = acc;                          // s[a_local][w_local]
    }
    __syncthreads();
#pragma unroll
    for (int p = 0; p < 4; ++p) {
        int wr = r8 + (p << 3);
        out[(b << 17) | ((w0 + wr) << 9) | (a0 + wl)] = s[wl][wr];  // coalesced in a
    }
}

extern "C" void kernel_launch(void* const* d_in, const int* in_sizes, int n_in,
                              void* d_out, int out_size, void* d_ws, size_t ws_size,
                              hipStream_t stream) {
    const float* img = (const float*)d_in[0];
    float* out = (float*)d_out;
    float* imT = (float*)d_ws;                    // 1 MB
    float* ws2 = (float*)d_ws + (1 << 18);        // 16.8 MB: [q][b][a][w]
    transpose_k<<<dim3(256),  dim3(256), 0, stream>>>(img, imT);
    radon_k   <<<dim3(2048), dim3(512), 0, stream>>>(img, imT, ws2);
    reduce_k  <<<dim3(512),  dim3(256), 0, stream>>>(ws2, out);
}